// Round 1
// baseline (359.772 us; speedup 1.0000x reference)
//
#include <hip/hip_runtime.h>

// AR(16) sequence generation, out (B=4096, T=8192) fp32.
// Strategy: time-segmented with zero-state warmup. Recurrence is contractive
// (char. roots magnitude <= 1/1.1), so influence of state decays ~0.909^k;
// W=256 warmup steps => state error ~2.5e-11 (threshold is 0.48).
// Segment 0 starts from the true initial state (exact, no warmup).

#define SEG_L 256   // main (output-producing) steps per segment
#define SEG_W 256   // warmup steps (zero-init), segments s>=1 only

// One recurrence step. Window invariant: at rotation k, y[t-16+i] == w[(k+i)&15].
// Dependent terms (i=14,15 -> values produced 2 and 1 steps ago) are applied
// LAST so the per-step critical path is ~2 FMA latencies; the rest is a
// 4-way independent tree the scheduler can hoist.
__device__ __forceinline__ float arstep(const float (&c)[16], const float (&w)[16],
                                        int k, float e) {
    float p0 = fmaf(c[0],  w[(k + 0)  & 15], e);
    float p1 =      c[1] * w[(k + 1)  & 15];
    float p2 =      c[2] * w[(k + 2)  & 15];
    float p3 =      c[3] * w[(k + 3)  & 15];
    p0 = fmaf(c[4],  w[(k + 4)  & 15], p0);
    p1 = fmaf(c[5],  w[(k + 5)  & 15], p1);
    p2 = fmaf(c[6],  w[(k + 6)  & 15], p2);
    p3 = fmaf(c[7],  w[(k + 7)  & 15], p3);
    p0 = fmaf(c[8],  w[(k + 8)  & 15], p0);
    p1 = fmaf(c[9],  w[(k + 9)  & 15], p1);
    p2 = fmaf(c[10], w[(k + 10) & 15], p2);
    p3 = fmaf(c[11], w[(k + 11) & 15], p3);
    p0 = fmaf(c[12], w[(k + 12) & 15], p0);
    p1 = fmaf(c[13], w[(k + 13) & 15], p1);
    p0 += p2;
    p1 += p3;
    p0 += p1;
    p0 = fmaf(c[14], w[(k + 14) & 15], p0);   // critical-path tail
    return fmaf(c[15], w[(k + 15) & 15], p0); // newest value last
}

__global__ __launch_bounds__(256, 2)
void ARModel_27925877359180_kernel(const float* __restrict__ init,   // (B,16)
                                   const float* __restrict__ coeff,  // (16)
                                   const float* __restrict__ lns,    // (1)
                                   const float* __restrict__ noise,  // (TN,B)
                                   float* __restrict__ out,          // (B,T)
                                   int B, int TN, int T, int nbc)
{
    const int blk = blockIdx.x;
    const int s   = blk / nbc;                       // segment index
    const int b   = (blk % nbc) * blockDim.x + threadIdx.x;
    if (b >= B) return;

    float c[16];
#pragma unroll
    for (int i = 0; i < 16; ++i) c[i] = coeff[i];
    const float nstd = expf(lns[0]);

    const int start = s * SEG_L;                     // first main noise index
    const int len   = min(SEG_L, TN - start);        // 256, except 240 for last seg

    float w[16];
    const float* np_;

    if (s == 0) {
        // exact initial state; also emit out[b, 0:16]
        const float4* i4 = (const float4*)(init + (size_t)b * 16);
        float4 a0 = i4[0], a1 = i4[1], a2 = i4[2], a3 = i4[3];
        w[0]  = a0.x; w[1]  = a0.y; w[2]  = a0.z; w[3]  = a0.w;
        w[4]  = a1.x; w[5]  = a1.y; w[6]  = a1.z; w[7]  = a1.w;
        w[8]  = a2.x; w[9]  = a2.y; w[10] = a2.z; w[11] = a2.w;
        w[12] = a3.x; w[13] = a3.y; w[14] = a3.z; w[15] = a3.w;
        float4* o4 = (float4*)(out + (size_t)b * T);
        o4[0] = a0; o4[1] = a1; o4[2] = a2; o4[3] = a3;
        np_ = noise + b;
    } else {
        // zero-state warmup over the previous SEG_W noise steps
#pragma unroll
        for (int i = 0; i < 16; ++i) w[i] = 0.0f;
        np_ = noise + (size_t)(start - SEG_W) * B + b;
        for (int ch = 0; ch < SEG_W / 16; ++ch) {
#pragma unroll
            for (int k = 0; k < 16; ++k) {
                float e = np_[(size_t)k * B];
                w[k] = arstep(c, w, k, e * nstd);
            }
            np_ += (size_t)16 * B;
        }
    }

    // main loop: len steps (multiple of 16), write out[b, 16+start ... )
    float* op = out + (size_t)b * T + 16 + start;
    const int nch = len / 16;
    for (int ch = 0; ch < nch; ++ch) {
        float buf[16];
#pragma unroll
        for (int k = 0; k < 16; ++k) {
            float e = np_[(size_t)k * B];
            float v = arstep(c, w, k, e * nstd);
            w[k]   = v;
            buf[k] = v;
        }
        np_ += (size_t)16 * B;
        float4* o4 = (float4*)op;
#pragma unroll
        for (int q = 0; q < 4; ++q) o4[q] = ((const float4*)buf)[q];
        op += 16;
    }
}

extern "C" void kernel_launch(void* const* d_in, const int* in_sizes, int n_in,
                              void* d_out, int out_size, void* d_ws, size_t ws_size,
                              hipStream_t stream) {
    const float* init  = (const float*)d_in[0];   // (B,16)
    const float* coeff = (const float*)d_in[1];   // (16)
    const float* lns   = (const float*)d_in[2];   // (1)
    const float* noise = (const float*)d_in[3];   // (TN,B)
    float* out = (float*)d_out;                   // (B,T) fp32

    const int B   = in_sizes[0] / 16;             // 4096
    const int TN  = in_sizes[3] / B;              // 8176
    const int T   = TN + 16;                      // 8192
    const int S   = (TN + SEG_L - 1) / SEG_L;     // 32
    const int nbc = (B + 255) / 256;              // 16

    dim3 grid(nbc * S), block(256);
    hipLaunchKernelGGL(ARModel_27925877359180_kernel, grid, block, 0, stream,
                       init, coeff, lns, noise, out, B, TN, T, nbc);
}

// Round 2
// 310.420 us; speedup vs baseline: 1.1590x; 1.1590x over previous
//
#include <hip/hip_runtime.h>

// AR(16) sequence generation, out (B=4096, T=8192) fp32.
// Time-segmented with zero-state warmup (recurrence is contractive: char roots
// <= 1/1.1 => 0.909^128 ~ 5e-6 decay over the 128-step warmup; threshold 0.48).
// R2: SEG 256->128 (2x waves, 16/CU) + double-buffered prefetch of the 16
// strided noise loads per chunk to hide HBM latency behind compute.

#define SEG_L 128   // main (output-producing) steps per segment
#define SEG_W 128   // warmup steps (zero-init), segments s>=1 only

// One recurrence step. Window invariant: at rotation k, y[t-16+i] == w[(k+i)&15].
// Dependent terms (i=14,15 -> produced 2 and 1 steps ago) applied LAST so the
// per-step critical path is ~2 FMA latencies; the rest is a 4-way tree.
__device__ __forceinline__ float arstep(const float (&c)[16], const float (&w)[16],
                                        int k, float e) {
    float p0 = fmaf(c[0],  w[(k + 0)  & 15], e);
    float p1 =      c[1] * w[(k + 1)  & 15];
    float p2 =      c[2] * w[(k + 2)  & 15];
    float p3 =      c[3] * w[(k + 3)  & 15];
    p0 = fmaf(c[4],  w[(k + 4)  & 15], p0);
    p1 = fmaf(c[5],  w[(k + 5)  & 15], p1);
    p2 = fmaf(c[6],  w[(k + 6)  & 15], p2);
    p3 = fmaf(c[7],  w[(k + 7)  & 15], p3);
    p0 = fmaf(c[8],  w[(k + 8)  & 15], p0);
    p1 = fmaf(c[9],  w[(k + 9)  & 15], p1);
    p2 = fmaf(c[10], w[(k + 10) & 15], p2);
    p3 = fmaf(c[11], w[(k + 11) & 15], p3);
    p0 = fmaf(c[12], w[(k + 12) & 15], p0);
    p1 = fmaf(c[13], w[(k + 13) & 15], p1);
    p0 += p2;
    p1 += p3;
    p0 += p1;
    p0 = fmaf(c[14], w[(k + 14) & 15], p0);   // critical-path tail
    return fmaf(c[15], w[(k + 15) & 15], p0); // newest value last
}

// 16 strided loads (one chunk of noise for this lane), pre-scaled by nstd.
__device__ __forceinline__ void loadchunk(float (&buf)[16], const float* __restrict__ p,
                                          int B, float nstd) {
#pragma unroll
    for (int k = 0; k < 16; ++k) buf[k] = p[(size_t)k * B] * nstd;
}

__global__ __launch_bounds__(256, 4)
void ARModel_27925877359180_kernel(const float* __restrict__ init,   // (B,16)
                                   const float* __restrict__ coeff,  // (16)
                                   const float* __restrict__ lns,    // (1)
                                   const float* __restrict__ noise,  // (TN,B)
                                   float* __restrict__ out,          // (B,T)
                                   int B, int TN, int T, int nbc)
{
    const int blk = blockIdx.x;
    const int s   = blk / nbc;                       // segment index
    const int b   = (blk % nbc) * blockDim.x + threadIdx.x;
    if (b >= B) return;

    float c[16];
#pragma unroll
    for (int i = 0; i < 16; ++i) c[i] = coeff[i];
    const float nstd = expf(lns[0]);

    const int start  = s * SEG_L;                    // first main noise index
    const int len    = min(SEG_L, TN - start);       // 128, except tail (112)
    const int wsteps = (s == 0) ? 0 : SEG_W;

    float w[16];
    const float* np_ = noise + (size_t)(start - wsteps) * B + b;

    if (s == 0) {
        // exact initial state; also emit out[b, 0:16]
        const float4* i4 = (const float4*)(init + (size_t)b * 16);
        float4 a0 = i4[0], a1 = i4[1], a2 = i4[2], a3 = i4[3];
        w[0]  = a0.x; w[1]  = a0.y; w[2]  = a0.z; w[3]  = a0.w;
        w[4]  = a1.x; w[5]  = a1.y; w[6]  = a1.z; w[7]  = a1.w;
        w[8]  = a2.x; w[9]  = a2.y; w[10] = a2.z; w[11] = a2.w;
        w[12] = a3.x; w[13] = a3.y; w[14] = a3.z; w[15] = a3.w;
        float4* o4 = (float4*)(out + (size_t)b * T);
        o4[0] = a0; o4[1] = a1; o4[2] = a2; o4[3] = a3;
    } else {
#pragma unroll
        for (int i = 0; i < 16; ++i) w[i] = 0.0f;
    }

    const int nch = (wsteps + len) / 16;             // total chunks
    const int wch = wsteps / 16;                     // warmup chunks (no store)
    float* op = out + (size_t)b * T + 16 + start;

    float bufA[16], bufB[16];
    loadchunk(bufA, np_, B, nstd);                   // prefetch chunk 0
    np_ += (size_t)16 * B;

#pragma unroll 2
    for (int ch = 0; ch < nch; ++ch) {
        if (ch + 1 < nch) {                          // prefetch next chunk
            loadchunk(bufB, np_, B, nstd);
            np_ += (size_t)16 * B;
        }
#pragma unroll
        for (int k = 0; k < 16; ++k)
            w[k] = arstep(c, w, k, bufA[k]);
        if (ch >= wch) {                             // w[0..15] is chronological
            float4* o4 = (float4*)op;
#pragma unroll
            for (int q = 0; q < 4; ++q) o4[q] = ((const float4*)w)[q];
            op += 16;
        }
#pragma unroll
        for (int k = 0; k < 16; ++k) bufA[k] = bufB[k];
    }
}

extern "C" void kernel_launch(void* const* d_in, const int* in_sizes, int n_in,
                              void* d_out, int out_size, void* d_ws, size_t ws_size,
                              hipStream_t stream) {
    const float* init  = (const float*)d_in[0];   // (B,16)
    const float* coeff = (const float*)d_in[1];   // (16)
    const float* lns   = (const float*)d_in[2];   // (1)
    const float* noise = (const float*)d_in[3];   // (TN,B)
    float* out = (float*)d_out;                   // (B,T) fp32

    const int B   = in_sizes[0] / 16;             // 4096
    const int TN  = in_sizes[3] / B;              // 8176
    const int T   = TN + 16;                      // 8192
    const int S   = (TN + SEG_L - 1) / SEG_L;     // 64
    const int nbc = (B + 255) / 256;              // 16

    dim3 grid(nbc * S), block(256);
    hipLaunchKernelGGL(ARModel_27925877359180_kernel, grid, block, 0, stream,
                       init, coeff, lns, noise, out, B, TN, T, nbc);
}